// Round 1
// baseline (423.376 us; speedup 1.0000x reference)
//
#include <hip/hip_runtime.h>
#include <math.h>

__device__ __forceinline__ float leaky(float v){ return v > 0.f ? v : 0.2f*v; }

__device__ __forceinline__ float wredsum(float v){
  #pragma unroll
  for (int o=32;o>0;o>>=1) v += __shfl_xor(v,o,64);
  return v;
}

// ---------------- graph CSR build (by dst) ----------------
__global__ void k_zero(int* p, int n){
  int i = blockIdx.x*blockDim.x + threadIdx.x;
  if (i < n) p[i] = 0;
}

__global__ void k_hist(const int* __restrict__ dst, int* __restrict__ deg, int E){
  int i = blockIdx.x*blockDim.x + threadIdx.x;
  if (i < E) atomicAdd(&deg[dst[i]], 1);
}

__global__ __launch_bounds__(1024) void k_scan(const int* __restrict__ deg, int* __restrict__ off,
                                               int* __restrict__ cur, int N){
  __shared__ int part[1024];
  int t = threadIdx.x;
  int chunk = (N + 1023) >> 10;
  int c0 = t * chunk;
  int sum = 0;
  for (int i=0;i<chunk;i++){ int idx=c0+i; if (idx < N) sum += deg[idx]; }
  part[t] = sum;
  __syncthreads();
  for (int o=1;o<1024;o<<=1){
    int v = (t >= o) ? part[t-o] : 0;
    __syncthreads();
    part[t] += v;
    __syncthreads();
  }
  int run = part[t] - sum;   // exclusive prefix of this chunk
  for (int i=0;i<chunk;i++){
    int idx = c0+i;
    if (idx < N){ off[idx] = run; cur[idx] = run; run += deg[idx]; }
  }
  if (t == 1023) off[N] = part[1023];
}

__global__ void k_scatter(const int* __restrict__ src, const int* __restrict__ dst,
                          int* __restrict__ cur, int* __restrict__ srcs, int E){
  int i = blockIdx.x*blockDim.x + threadIdx.x;
  if (i < E){ int p = atomicAdd(&cur[dst[i]], 1); srcs[p] = src[i]; }
}

// ---------------- fp32 GEMM, K=64 fixed, 64x64 tiles ----------------
// A [M,64] row-major, B [64,Nn] row-major, C [M,Nn]
__global__ __launch_bounds__(256) void k_gemm64(const float* __restrict__ A, const float* __restrict__ B,
                                                float* __restrict__ C, int M, int Nn){
  __shared__ __align__(16) float As[64][68];
  __shared__ __align__(16) float Bs[64][68];
  const int m0 = blockIdx.x*64, c0 = blockIdx.y*64;
  const int tid = threadIdx.x;
  #pragma unroll
  for (int q=0;q<4;q++){
    int lin = tid + q*256;
    int r = lin >> 4, c4 = (lin & 15) << 2;
    float4 va = make_float4(0.f,0.f,0.f,0.f);
    if (m0 + r < M) va = *reinterpret_cast<const float4*>(A + (size_t)(m0+r)*64 + c4);
    *reinterpret_cast<float4*>(&As[r][c4]) = va;
    float4 vb = *reinterpret_cast<const float4*>(B + (size_t)r*Nn + c0 + c4);
    *reinterpret_cast<float4*>(&Bs[r][c4]) = vb;
  }
  __syncthreads();
  const int tx = tid & 15, ty = tid >> 4;
  float acc[4][4] = {};
  #pragma unroll
  for (int k=0;k<64;k+=4){
    float av[4][4], bv[4][4];
    #pragma unroll
    for (int i=0;i<4;i++){
      float4 t = *reinterpret_cast<const float4*>(&As[ty*4+i][k]);
      av[i][0]=t.x; av[i][1]=t.y; av[i][2]=t.z; av[i][3]=t.w;
    }
    #pragma unroll
    for (int kk=0;kk<4;kk++){
      float4 t = *reinterpret_cast<const float4*>(&Bs[k+kk][tx*4]);
      bv[kk][0]=t.x; bv[kk][1]=t.y; bv[kk][2]=t.z; bv[kk][3]=t.w;
    }
    #pragma unroll
    for (int kk=0;kk<4;kk++)
      #pragma unroll
      for (int i=0;i<4;i++)
        #pragma unroll
        for (int j=0;j<4;j++)
          acc[i][j] += av[i][kk]*bv[kk][j];
  }
  #pragma unroll
  for (int i=0;i<4;i++){
    int row = m0 + ty*4 + i;
    if (row < M){
      float4 v = make_float4(acc[i][0],acc[i][1],acc[i][2],acc[i][3]);
      *reinterpret_cast<float4*>(C + (size_t)row*Nn + c0 + tx*4) = v;
    }
  }
}

// ---------------- attention coefficients ----------------
// layer1: el[n,h] = sum_d f1[n,h,d]*al[h,d]   (one wave per node, lane=d)
__global__ __launch_bounds__(256) void k_coef1(const float* __restrict__ f1, const float* __restrict__ al,
                                               const float* __restrict__ ar, float* __restrict__ el,
                                               float* __restrict__ er, int N){
  int n = blockIdx.x*4 + (threadIdx.x>>6);
  int lane = threadIdx.x & 63;
  if (n >= N) return;
  const float* fp = f1 + (size_t)n*640;
  #pragma unroll
  for (int k=0;k<10;k++){
    float f = fp[k*64+lane];
    float pl = wredsum(f*al[k*64+lane]);
    float pr = wredsum(f*ar[k*64+lane]);
    if (lane==0){ el[n*10+k]=pl; er[n*10+k]=pr; }
  }
}

// layer2: el[n] = sum_{128} f2[n,:]*al2
__global__ __launch_bounds__(256) void k_coef2(const float* __restrict__ f2, const float* __restrict__ al,
                                               const float* __restrict__ ar, float* __restrict__ el,
                                               float* __restrict__ er, int N){
  int n = blockIdx.x*4 + (threadIdx.x>>6);
  int lane = threadIdx.x & 63;
  if (n >= N) return;
  float x0 = f2[(size_t)n*128+lane], x1 = f2[(size_t)n*128+64+lane];
  float pl = wredsum(x0*al[lane] + x1*al[64+lane]);
  float pr = wredsum(x0*ar[lane] + x1*ar[64+lane]);
  if (lane==0){ el[n]=pl; er[n]=pr; }
}

// ---------------- layer1 edge aggregation: one wave per node, lanes 0-9 = heads for softmax ----------------
__global__ __launch_bounds__(256) void k_edge1(const float* __restrict__ f1, const float* __restrict__ el,
                                               const float* __restrict__ er, const int* __restrict__ off,
                                               const int* __restrict__ srcs, const float* __restrict__ b1,
                                               float* __restrict__ hout, int N){
  int n = blockIdx.x*4 + (threadIdx.x>>6);
  int lane = threadIdx.x & 63;
  if (n >= N) return;
  int beg = off[n], end = off[n+1];
  float erh = (lane < 10) ? er[n*10+lane] : 0.f;
  // pass A: online softmax stats per head (lanes 0..9)
  float m = -INFINITY, s = 0.f;
  for (int e=beg; e<end; ++e){
    int sv = srcs[e];
    if (lane < 10){
      float v = leaky(el[sv*10+lane] + erh);
      float mn = fmaxf(m, v);
      s = s*__expf(m-mn) + __expf(v-mn);
      m = mn;
    }
  }
  float rs = 1.f / s;  // only meaningful on lanes<10 with deg>0 (loop below empty otherwise)
  // pass B: weighted gather-accumulate; lane = d, acc[k] = head k
  float acc[10];
  #pragma unroll
  for (int k=0;k<10;k++) acc[k]=0.f;
  for (int e=beg; e<end; ++e){
    int sv = srcs[e];
    float wv = 0.f;
    if (lane < 10){
      float v = leaky(el[sv*10+lane] + erh);
      wv = __expf(v - m) * rs;
    }
    const float* fp = f1 + (size_t)sv*640;
    #pragma unroll
    for (int k=0;k<10;k++){
      float wk = __shfl(wv, k, 64);
      acc[k] += wk * fp[k*64+lane];
    }
  }
  // epilogue: +bias, relu, sum over heads
  float o = 0.f;
  #pragma unroll
  for (int k=0;k<10;k++){
    float v = acc[k] + b1[k*64+lane];
    o += fmaxf(v, 0.f);
  }
  hout[(size_t)n*64 + lane] = o;
}

// ---------------- layer2 edge aggregation: one wave per node, H=1, D=128 ----------------
__global__ __launch_bounds__(256) void k_edge2(const float* __restrict__ f2, const float* __restrict__ el,
                                               const float* __restrict__ er, const int* __restrict__ off,
                                               const int* __restrict__ srcs, const float* __restrict__ b2,
                                               float* __restrict__ h2, int N){
  int n = blockIdx.x*4 + (threadIdx.x>>6);
  int lane = threadIdx.x & 63;
  if (n >= N) return;
  int beg = off[n], end = off[n+1];
  float ern = er[n];
  // pass A: lane-parallel online softmax over edges, then butterfly merge
  float m = -INFINITY, s = 0.f;
  for (int e=beg+lane; e<end; e+=64){
    float v = leaky(el[srcs[e]] + ern);
    float mn = fmaxf(m, v);
    s = s*__expf(m-mn) + __expf(v-mn);
    m = mn;
  }
  #pragma unroll
  for (int o=32;o>0;o>>=1){
    float mo = __shfl_xor(m,o,64);
    float so = __shfl_xor(s,o,64);
    float mn = fmaxf(m,mo);
    float sa = (s  > 0.f) ? s *__expf(m -mn) : 0.f;
    float sb = (so > 0.f) ? so*__expf(mo-mn) : 0.f;
    s = sa + sb; m = mn;
  }
  float rs = (s > 0.f) ? 1.f/s : 0.f;
  float a0 = 0.f, a1 = 0.f;
  for (int e=beg; e<end; ++e){
    int sv = srcs[e];
    float wv = __expf(leaky(el[sv] + ern) - m) * rs;
    a0 += wv * f2[(size_t)sv*128 + lane];
    a1 += wv * f2[(size_t)sv*128 + 64 + lane];
  }
  h2[(size_t)n*128 + lane]      = fmaxf(a0 + b2[lane],    0.f);
  h2[(size_t)n*128 + 64 + lane] = fmaxf(a1 + b2[64+lane], 0.f);
}

// ---------------- per-graph max readout + 2-layer MLP ----------------
__device__ __forceinline__ int lowerb(const int* a, int n, int v){
  int lo=0, hi=n;
  while (lo < hi){ int mid=(lo+hi)>>1; if (a[mid] < v) lo=mid+1; else hi=mid; }
  return lo;
}

__global__ __launch_bounds__(128) void k_readout(const float* __restrict__ h2, const int* __restrict__ gid,
                                                 const float* __restrict__ lw1, const float* __restrict__ lb1,
                                                 const float* __restrict__ lw2, const float* __restrict__ lb2,
                                                 float* __restrict__ out, int N){
  int b = blockIdx.x, t = threadIdx.x;   // t = channel 0..127
  int lo = lowerb(gid, N, b), hi = lowerb(gid, N, b+1);
  float mx = -INFINITY;
  for (int n=lo; n<hi; ++n) mx = fmaxf(mx, h2[(size_t)n*128 + t]);
  if (hi == lo) mx = 0.f;   // empty-graph / isfinite safety
  __shared__ float gs[128];
  __shared__ float ys[128];
  gs[t] = mx;
  __syncthreads();
  float y = lb1[t];
  for (int k=0;k<128;k++) y += gs[k]*lw1[k*128 + t];
  y = fmaxf(y, 0.f);
  ys[t] = y * lw2[t];
  __syncthreads();
  for (int o=64;o>0;o>>=1){
    if (t < o) ys[t] += ys[t+o];
    __syncthreads();
  }
  if (t == 0) out[b] = fmaxf(ys[0] + lb2[0], 0.f);
}

extern "C" void kernel_launch(void* const* d_in, const int* in_sizes, int n_in,
                              void* d_out, int out_size, void* d_ws, size_t ws_size,
                              hipStream_t stream){
  const float* x   = (const float*)d_in[0];
  const int*   src = (const int*)d_in[1];
  const int*   dst = (const int*)d_in[2];
  const int*   gid = (const int*)d_in[3];
  const float* W1  = (const float*)d_in[4];
  const float* al1 = (const float*)d_in[5];
  const float* ar1 = (const float*)d_in[6];
  const float* b1  = (const float*)d_in[7];
  const float* W2  = (const float*)d_in[8];
  const float* al2 = (const float*)d_in[9];
  const float* ar2 = (const float*)d_in[10];
  const float* b2  = (const float*)d_in[11];
  const float* lw1 = (const float*)d_in[12];
  const float* lb1 = (const float*)d_in[13];
  const float* lw2 = (const float*)d_in[14];
  const float* lb2 = (const float*)d_in[15];
  float* out = (float*)d_out;

  const int N = in_sizes[0] / 64;
  const int E = in_sizes[1];
  const int G = out_size;

  char* w = (char*)d_ws;
  size_t p = 0;
  auto alloc = [&](size_t bytes)->char*{ char* r = w + p; p += (bytes + 255) & ~size_t(255); return r; };
  int*   deg  = (int*)alloc((size_t)N*4);
  int*   off  = (int*)alloc((size_t)(N+1)*4);
  int*   cur  = (int*)alloc((size_t)N*4);
  int*   srcs = (int*)alloc((size_t)E*4);
  float* el1  = (float*)alloc((size_t)N*10*4);
  float* er1  = (float*)alloc((size_t)N*10*4);
  float* h1   = (float*)alloc((size_t)N*64*4);
  float* f1   = (float*)alloc((size_t)N*640*4);
  // layer-2 buffers alias the (dead-after-edge1) f1 region
  float* f2  = f1;                    // N*128 floats
  float* h2  = f1 + (size_t)N*128;    // N*128 floats
  float* el2 = el1;
  float* er2 = er1;

  const int nwB = (N + 3) / 4;   // 4 waves (nodes) per 256-thread block

  k_zero   <<<dim3((N+255)/256), dim3(256), 0, stream>>>(deg, N);
  k_hist   <<<dim3((E+255)/256), dim3(256), 0, stream>>>(dst, deg, E);
  k_scan   <<<dim3(1),           dim3(1024),0, stream>>>(deg, off, cur, N);
  k_scatter<<<dim3((E+255)/256), dim3(256), 0, stream>>>(src, dst, cur, srcs, E);

  k_gemm64 <<<dim3((N+63)/64, 10), dim3(256), 0, stream>>>(x, W1, f1, N, 640);
  k_coef1  <<<dim3(nwB), dim3(256), 0, stream>>>(f1, al1, ar1, el1, er1, N);
  k_edge1  <<<dim3(nwB), dim3(256), 0, stream>>>(f1, el1, er1, off, srcs, b1, h1, N);

  k_gemm64 <<<dim3((N+63)/64, 2), dim3(256), 0, stream>>>(h1, W2, f2, N, 128);
  k_coef2  <<<dim3(nwB), dim3(256), 0, stream>>>(f2, al2, ar2, el2, er2, N);
  k_edge2  <<<dim3(nwB), dim3(256), 0, stream>>>(f2, el2, er2, off, srcs, b2, h2, N);

  k_readout<<<dim3(G), dim3(128), 0, stream>>>(h2, gid, lw1, lb1, lw2, lb2, out, N);
}

// Round 2
// 374.701 us; speedup vs baseline: 1.1299x; 1.1299x over previous
//
#include <hip/hip_runtime.h>
#include <math.h>

__device__ __forceinline__ float leaky(float v){ return v > 0.f ? v : 0.2f*v; }

__device__ __forceinline__ float wredsum(float v){
  #pragma unroll
  for (int o=32;o>0;o>>=1) v += __shfl_xor(v,o,64);
  return v;
}

// ---------------- graph CSR build (by dst) ----------------
__global__ void k_zero(int* p, int n){
  int i = blockIdx.x*blockDim.x + threadIdx.x;
  if (i < n) p[i] = 0;
}

__global__ void k_hist(const int* __restrict__ dst, int* __restrict__ deg, int E){
  int i = blockIdx.x*blockDim.x + threadIdx.x;
  if (i < E) atomicAdd(&deg[dst[i]], 1);
}

__global__ __launch_bounds__(1024) void k_scan(const int* __restrict__ deg, int* __restrict__ off,
                                               int* __restrict__ cur, int N){
  __shared__ int part[1024];
  int t = threadIdx.x;
  int chunk = (N + 1023) >> 10;
  int c0 = t * chunk;
  int sum = 0;
  for (int i=0;i<chunk;i++){ int idx=c0+i; if (idx < N) sum += deg[idx]; }
  part[t] = sum;
  __syncthreads();
  for (int o=1;o<1024;o<<=1){
    int v = (t >= o) ? part[t-o] : 0;
    __syncthreads();
    part[t] += v;
    __syncthreads();
  }
  int run = part[t] - sum;   // exclusive prefix of this chunk
  for (int i=0;i<chunk;i++){
    int idx = c0+i;
    if (idx < N){ off[idx] = run; cur[idx] = run; run += deg[idx]; }
  }
  if (t == 1023) off[N] = part[1023];
}

__global__ void k_scatter(const int* __restrict__ src, const int* __restrict__ dst,
                          int* __restrict__ cur, int* __restrict__ srcs, int E){
  int i = blockIdx.x*blockDim.x + threadIdx.x;
  if (i < E){ int p = atomicAdd(&cur[dst[i]], 1); srcs[p] = src[i]; }
}

// ---------------- fp32 GEMM, K=64 fixed, 64x64 tiles, optional fused attn-coef ----------------
// A [M,64] row-major, B [64,Nn] row-major, C [M,Nn]
// If el != nullptr: head h = blockIdx.y (64-col head tiles); writes
// el[row*H+h] = sum_d C[row, h*64+d]*al[h*64+d], er likewise. Exclusive writer per (row,h).
__global__ __launch_bounds__(256) void k_gemm64(const float* __restrict__ A, const float* __restrict__ B,
                                                float* __restrict__ C, int M, int Nn,
                                                const float* __restrict__ al, const float* __restrict__ ar,
                                                float* __restrict__ el, float* __restrict__ er, int H){
  __shared__ __align__(16) float As[64][68];
  __shared__ __align__(16) float Bs[64][68];
  const int m0 = blockIdx.x*64, c0 = blockIdx.y*64;
  const int tid = threadIdx.x;
  #pragma unroll
  for (int q=0;q<4;q++){
    int lin = tid + q*256;
    int r = lin >> 4, c4 = (lin & 15) << 2;
    float4 va = make_float4(0.f,0.f,0.f,0.f);
    if (m0 + r < M) va = *reinterpret_cast<const float4*>(A + (size_t)(m0+r)*64 + c4);
    *reinterpret_cast<float4*>(&As[r][c4]) = va;
    float4 vb = *reinterpret_cast<const float4*>(B + (size_t)r*Nn + c0 + c4);
    *reinterpret_cast<float4*>(&Bs[r][c4]) = vb;
  }
  __syncthreads();
  const int tx = tid & 15, ty = tid >> 4;
  float acc[4][4] = {};
  #pragma unroll
  for (int k=0;k<64;k+=4){
    float av[4][4], bv[4][4];
    #pragma unroll
    for (int i=0;i<4;i++){
      float4 t = *reinterpret_cast<const float4*>(&As[ty*4+i][k]);
      av[i][0]=t.x; av[i][1]=t.y; av[i][2]=t.z; av[i][3]=t.w;
    }
    #pragma unroll
    for (int kk=0;kk<4;kk++){
      float4 t = *reinterpret_cast<const float4*>(&Bs[k+kk][tx*4]);
      bv[kk][0]=t.x; bv[kk][1]=t.y; bv[kk][2]=t.z; bv[kk][3]=t.w;
    }
    #pragma unroll
    for (int kk=0;kk<4;kk++)
      #pragma unroll
      for (int i=0;i<4;i++)
        #pragma unroll
        for (int j=0;j<4;j++)
          acc[i][j] += av[i][kk]*bv[kk][j];
  }
  #pragma unroll
  for (int i=0;i<4;i++){
    int row = m0 + ty*4 + i;
    if (row < M){
      float4 v = make_float4(acc[i][0],acc[i][1],acc[i][2],acc[i][3]);
      *reinterpret_cast<float4*>(C + (size_t)row*Nn + c0 + tx*4) = v;
    }
  }
  if (el){
    const int h = blockIdx.y;
    float alv[4], arv[4];
    #pragma unroll
    for (int j=0;j<4;j++){ alv[j] = al[c0 + tx*4 + j]; arv[j] = ar[c0 + tx*4 + j]; }
    #pragma unroll
    for (int i=0;i<4;i++){
      float pl = acc[i][0]*alv[0] + acc[i][1]*alv[1] + acc[i][2]*alv[2] + acc[i][3]*alv[3];
      float pr = acc[i][0]*arv[0] + acc[i][1]*arv[1] + acc[i][2]*arv[2] + acc[i][3]*arv[3];
      #pragma unroll
      for (int o=8;o>0;o>>=1){ pl += __shfl_xor(pl,o,16); pr += __shfl_xor(pr,o,16); }
      int row = m0 + ty*4 + i;
      if (tx == 0 && row < M){
        el[(size_t)row*H + h] = pl;
        er[(size_t)row*H + h] = pr;
      }
    }
  }
}

// layer2 coef: el[n] = sum_{128} f2[n,:]*al2 (one wave per node)
__global__ __launch_bounds__(256) void k_coef2(const float* __restrict__ f2, const float* __restrict__ al,
                                               const float* __restrict__ ar, float* __restrict__ el,
                                               float* __restrict__ er, int N){
  int n = blockIdx.x*4 + (threadIdx.x>>6);
  int lane = threadIdx.x & 63;
  if (n >= N) return;
  float x0 = f2[(size_t)n*128+lane], x1 = f2[(size_t)n*128+64+lane];
  float pl = wredsum(x0*al[lane] + x1*al[64+lane]);
  float pr = wredsum(x0*ar[lane] + x1*ar[64+lane]);
  if (lane==0){ el[n]=pl; er[n]=pr; }
}

// ---------------- layer1 edge aggregation ----------------
// One wave per node. Pass A: plain max-reduce (4-way unrolled, no exp chain).
// Pass B: fused exp + sum + weighted gather (2-way unrolled); normalize in epilogue.
__global__ __launch_bounds__(256) void k_edge1(const float* __restrict__ f1, const float* __restrict__ el,
                                               const float* __restrict__ er, const int* __restrict__ off,
                                               const int* __restrict__ srcs, const float* __restrict__ b1,
                                               float* __restrict__ hout, int N){
  int n = blockIdx.x*4 + (threadIdx.x>>6);
  int lane = threadIdx.x & 63;
  if (n >= N) return;
  const int beg = off[n], end = off[n+1];
  const bool hl = lane < 10;
  const float erh = hl ? er[n*10+lane] : 0.f;
  // pass A: m_h = leaky(max_e el[src,h] + er_h)  (max is order-free; leaky monotone)
  float m0=-INFINITY, m1=-INFINITY, m2=-INFINITY, m3=-INFINITY;
  int e = beg;
  for (; e+3<end; e+=4){
    int s0=srcs[e], s1=srcs[e+1], s2=srcs[e+2], s3=srcs[e+3];
    if (hl){
      m0 = fmaxf(m0, el[s0*10+lane]);
      m1 = fmaxf(m1, el[s1*10+lane]);
      m2 = fmaxf(m2, el[s2*10+lane]);
      m3 = fmaxf(m3, el[s3*10+lane]);
    }
  }
  for (; e<end; ++e) if (hl) m0 = fmaxf(m0, el[srcs[e]*10+lane]);
  const float m = leaky(fmaxf(fmaxf(m0,m1),fmaxf(m2,m3)) + erh);
  // pass B: fused exp + denom + gather-accumulate
  float s = 0.f;
  float acc[10];
  #pragma unroll
  for (int k=0;k<10;k++) acc[k] = 0.f;
  e = beg;
  for (; e+1<end; e+=2){
    int s0 = srcs[e], s1 = srcs[e+1];
    float w0 = 0.f, w1 = 0.f;
    if (hl){
      w0 = __expf(leaky(el[s0*10+lane]+erh) - m);
      w1 = __expf(leaky(el[s1*10+lane]+erh) - m);
      s += w0 + w1;
    }
    const float* fp0 = f1 + (size_t)s0*640 + lane;
    const float* fp1 = f1 + (size_t)s1*640 + lane;
    #pragma unroll
    for (int k=0;k<10;k++){
      float va = fp0[k*64];
      float vb = fp1[k*64];
      acc[k] += __shfl(w0,k,64)*va + __shfl(w1,k,64)*vb;
    }
  }
  if (e < end){
    int s0 = srcs[e];
    float w0 = 0.f;
    if (hl){
      w0 = __expf(leaky(el[s0*10+lane]+erh) - m);
      s += w0;
    }
    const float* fp0 = f1 + (size_t)s0*640 + lane;
    #pragma unroll
    for (int k=0;k<10;k++) acc[k] += __shfl(w0,k,64)*fp0[k*64];
  }
  const float rsv = (hl && s > 0.f) ? 1.f/s : 0.f;
  float o = 0.f;
  #pragma unroll
  for (int k=0;k<10;k++){
    float rk = __shfl(rsv,k,64);
    o += fmaxf(acc[k]*rk + b1[k*64+lane], 0.f);
  }
  hout[(size_t)n*64 + lane] = o;
}

// ---------------- layer2 edge aggregation: one wave per node, H=1, D=128 ----------------
__global__ __launch_bounds__(256) void k_edge2(const float* __restrict__ f2, const float* __restrict__ el,
                                               const float* __restrict__ er, const int* __restrict__ off,
                                               const int* __restrict__ srcs, const float* __restrict__ b2,
                                               float* __restrict__ h2, int N){
  int n = blockIdx.x*4 + (threadIdx.x>>6);
  int lane = threadIdx.x & 63;
  if (n >= N) return;
  const int beg = off[n], end = off[n+1];
  const float ern = er[n];
  // pass A: lane-parallel max + butterfly (max only — no exp chain)
  float mx = -INFINITY;
  for (int e=beg+lane; e<end; e+=64) mx = fmaxf(mx, el[srcs[e]]);
  #pragma unroll
  for (int o=32;o>0;o>>=1) mx = fmaxf(mx, __shfl_xor(mx,o,64));
  const float m = leaky(mx + ern);
  // pass B: fused exp + denom + gather (2-way unrolled); w identical on all lanes (broadcast loads)
  float s = 0.f, a0 = 0.f, a1 = 0.f;
  int e = beg;
  for (; e+1<end; e+=2){
    int s0 = srcs[e], s1 = srcs[e+1];
    float w0 = __expf(leaky(el[s0]+ern) - m);
    float w1 = __expf(leaky(el[s1]+ern) - m);
    s += w0 + w1;
    const float* p0 = f2 + (size_t)s0*128 + lane;
    const float* p1 = f2 + (size_t)s1*128 + lane;
    a0 += w0*p0[0]  + w1*p1[0];
    a1 += w0*p0[64] + w1*p1[64];
  }
  if (e < end){
    int s0 = srcs[e];
    float w0 = __expf(leaky(el[s0]+ern) - m);
    s += w0;
    const float* p0 = f2 + (size_t)s0*128 + lane;
    a0 += w0*p0[0];
    a1 += w0*p0[64];
  }
  const float rs = (s > 0.f) ? 1.f/s : 0.f;
  h2[(size_t)n*128 + lane]      = fmaxf(a0*rs + b2[lane],    0.f);
  h2[(size_t)n*128 + 64 + lane] = fmaxf(a1*rs + b2[64+lane], 0.f);
}

// ---------------- per-graph max readout + 2-layer MLP ----------------
__device__ __forceinline__ int lowerb(const int* a, int n, int v){
  int lo=0, hi=n;
  while (lo < hi){ int mid=(lo+hi)>>1; if (a[mid] < v) lo=mid+1; else hi=mid; }
  return lo;
}

__global__ __launch_bounds__(128) void k_readout(const float* __restrict__ h2, const int* __restrict__ gid,
                                                 const float* __restrict__ lw1, const float* __restrict__ lb1,
                                                 const float* __restrict__ lw2, const float* __restrict__ lb2,
                                                 float* __restrict__ out, int N){
  int b = blockIdx.x, t = threadIdx.x;   // t = channel 0..127
  int lo = lowerb(gid, N, b), hi = lowerb(gid, N, b+1);
  float mx = -INFINITY;
  for (int n=lo; n<hi; ++n) mx = fmaxf(mx, h2[(size_t)n*128 + t]);
  if (hi == lo) mx = 0.f;   // empty-graph / isfinite safety
  __shared__ float gs[128];
  __shared__ float ys[128];
  gs[t] = mx;
  __syncthreads();
  float y = lb1[t];
  for (int k=0;k<128;k++) y += gs[k]*lw1[k*128 + t];
  y = fmaxf(y, 0.f);
  ys[t] = y * lw2[t];
  __syncthreads();
  for (int o=64;o>0;o>>=1){
    if (t < o) ys[t] += ys[t+o];
    __syncthreads();
  }
  if (t == 0) out[b] = fmaxf(ys[0] + lb2[0], 0.f);
}

extern "C" void kernel_launch(void* const* d_in, const int* in_sizes, int n_in,
                              void* d_out, int out_size, void* d_ws, size_t ws_size,
                              hipStream_t stream){
  const float* x   = (const float*)d_in[0];
  const int*   src = (const int*)d_in[1];
  const int*   dst = (const int*)d_in[2];
  const int*   gid = (const int*)d_in[3];
  const float* W1  = (const float*)d_in[4];
  const float* al1 = (const float*)d_in[5];
  const float* ar1 = (const float*)d_in[6];
  const float* b1  = (const float*)d_in[7];
  const float* W2  = (const float*)d_in[8];
  const float* al2 = (const float*)d_in[9];
  const float* ar2 = (const float*)d_in[10];
  const float* b2  = (const float*)d_in[11];
  const float* lw1 = (const float*)d_in[12];
  const float* lb1 = (const float*)d_in[13];
  const float* lw2 = (const float*)d_in[14];
  const float* lb2 = (const float*)d_in[15];
  float* out = (float*)d_out;

  const int N = in_sizes[0] / 64;
  const int E = in_sizes[1];
  const int G = out_size;

  char* w = (char*)d_ws;
  size_t p = 0;
  auto alloc = [&](size_t bytes)->char*{ char* r = w + p; p += (bytes + 255) & ~size_t(255); return r; };
  int*   deg  = (int*)alloc((size_t)N*4);
  int*   off  = (int*)alloc((size_t)(N+1)*4);
  int*   cur  = (int*)alloc((size_t)N*4);
  int*   srcs = (int*)alloc((size_t)E*4);
  float* el1  = (float*)alloc((size_t)N*10*4);
  float* er1  = (float*)alloc((size_t)N*10*4);
  float* h1   = (float*)alloc((size_t)N*64*4);
  float* f1   = (float*)alloc((size_t)N*640*4);
  // layer-2 buffers alias the (dead-after-edge1) f1 region
  float* f2  = f1;                    // N*128 floats
  float* h2  = f1 + (size_t)N*128;    // N*128 floats
  float* el2 = el1;
  float* er2 = er1;

  const int nwB = (N + 3) / 4;   // 4 waves (nodes) per 256-thread block

  k_zero   <<<dim3((N+255)/256), dim3(256), 0, stream>>>(deg, N);
  k_hist   <<<dim3((E+255)/256), dim3(256), 0, stream>>>(dst, deg, E);
  k_scan   <<<dim3(1),           dim3(1024),0, stream>>>(deg, off, cur, N);
  k_scatter<<<dim3((E+255)/256), dim3(256), 0, stream>>>(src, dst, cur, srcs, E);

  // layer 1: GEMM with fused attention-coef epilogue (no separate coef pass)
  k_gemm64 <<<dim3((N+63)/64, 10), dim3(256), 0, stream>>>(x, W1, f1, N, 640, al1, ar1, el1, er1, 10);
  k_edge1  <<<dim3(nwB), dim3(256), 0, stream>>>(f1, el1, er1, off, srcs, b1, h1, N);

  // layer 2
  k_gemm64 <<<dim3((N+63)/64, 2), dim3(256), 0, stream>>>(h1, W2, f2, N, 128,
                                                          nullptr, nullptr, nullptr, nullptr, 1);
  k_coef2  <<<dim3(nwB), dim3(256), 0, stream>>>(f2, al2, ar2, el2, er2, N);
  k_edge2  <<<dim3(nwB), dim3(256), 0, stream>>>(f2, el2, er2, off, srcs, b2, h2, N);

  k_readout<<<dim3(G), dim3(128), 0, stream>>>(h2, gid, lw1, lb1, lw2, lb2, out, N);
}